// Round 4
// baseline (496.513 us; speedup 1.0000x reference)
//
#include <hip/hip_runtime.h>
#include <math.h>

// Problem constants (fixed by the reference):
#define NEXP 4               // n
#define STREAM 4096          // N*C
#define NOUT 24              // n*n + 2n
#define NTOK 16384           // B*L
#define SK_ITERS 20

// Kernel B tiling: barrier-free per-wave matvec.
//   Each wave owns T_W=4 tokens, computes all 24 outputs; lanes split K.
//   No LDS, no __syncthreads (R3 post-mortem: the compiler's vmcnt(0) drain
//   at every barrier serialized the staged pipeline to ~1.9 TB/s).
#define T_W 4                // tokens per wave
#define KSTEP 256            // floats of K per i-step (64 lanes x float4)
#define NSTEP (STREAM / KSTEP)    // 16

// ---------------------------------------------------------------------------
// Kernel A: phiT[j][k] = scale[k] * phi[k][j]   (24 x 4096, transposed+scaled)
// ---------------------------------------------------------------------------
__global__ __launch_bounds__(256) void k_transpose_scale(
    const float* __restrict__ phi, const float* __restrict__ scale,
    float* __restrict__ phiT) {
  int flat = blockIdx.x * 256 + threadIdx.x;   // 0..98303, flat = k*24 + j
  int k = flat / NOUT;
  int j = flat - k * NOUT;
  phiT[j * STREAM + k] = phi[flat] * scale[k];
}

// ---------------------------------------------------------------------------
// Kernel B: per token, sumsq + 24-way dot, m = dot/rms + bias -> m_buf
//   Wave-private: 4 tokens/wave, lane l owns k = i*256 + l*4 (.. +4).
//   x: 4 dwordx4/step, coalesced (wave covers 1 KB/token contiguous).
//   phi: 6 dwordx4 per j-tile, same coalescing; re-streamed per wave
//   (4-token reuse -> 1.57 GB L2 traffic, ~83% of per-XCD L2 ceiling).
//   Straight-line loads + FMAs, compiler pipelines with partial vmcnt.
// ---------------------------------------------------------------------------
__global__ __launch_bounds__(256) void k_matvec(
    const float* __restrict__ x, const float* __restrict__ phiT,
    const float* __restrict__ bias, float* __restrict__ m_buf) {
  const int w    = threadIdx.x >> 6;
  const int lane = threadIdx.x & 63;
  const int tok0 = (blockIdx.x * 4 + w) * T_W;

  const float4* x4    = (const float4*)x;
  const float4* phiT4 = (const float4*)phiT;

  float acc[T_W][NOUT];
  float ssq[T_W];
#pragma unroll
  for (int t = 0; t < T_W; t++) {
    ssq[t] = 0.0f;
#pragma unroll
    for (int j = 0; j < NOUT; j++) acc[t][j] = 0.0f;
  }

  for (int i = 0; i < NSTEP; i++) {
    const int kofs = i * (KSTEP / 4) + lane;   // float4 index within a row
    float4 xv[T_W];
#pragma unroll
    for (int t = 0; t < T_W; t++)
      xv[t] = x4[(size_t)(tok0 + t) * (STREAM / 4) + kofs];
#pragma unroll
    for (int t = 0; t < T_W; t++)
      ssq[t] += xv[t].x * xv[t].x + xv[t].y * xv[t].y +
                xv[t].z * xv[t].z + xv[t].w * xv[t].w;

#pragma unroll
    for (int jt = 0; jt < 4; jt++) {          // 4 tiles of 6 j-columns
      float4 pv[6];
#pragma unroll
      for (int jj = 0; jj < 6; jj++)
        pv[jj] = phiT4[(jt * 6 + jj) * (STREAM / 4) + kofs];
#pragma unroll
      for (int t = 0; t < T_W; t++) {
#pragma unroll
        for (int jj = 0; jj < 6; jj++) {
          float a = acc[t][jt * 6 + jj];
          a = fmaf(xv[t].x, pv[jj].x, a);
          a = fmaf(xv[t].y, pv[jj].y, a);
          a = fmaf(xv[t].z, pv[jj].z, a);
          a = fmaf(xv[t].w, pv[jj].w, a);
          acc[t][jt * 6 + jj] = a;
        }
      }
    }
  }

  // ---- butterfly reduce across the 64 lanes (all lanes end with totals) ----
#pragma unroll
  for (int d = 1; d < 64; d <<= 1) {
#pragma unroll
    for (int t = 0; t < T_W; t++) {
      ssq[t] += __shfl_xor(ssq[t], d, 64);
#pragma unroll
      for (int j = 0; j < NOUT; j++)
        acc[t][j] += __shfl_xor(acc[t][j], d, 64);
    }
  }

  // ---- write m: lane j stores column j of each token ----
#pragma unroll
  for (int t = 0; t < T_W; t++) {
    float inv = 1.0f / sqrtf(ssq[t] * (1.0f / STREAM) + 1e-20f);
#pragma unroll
    for (int j = 0; j < NOUT; j++) {
      if (lane == j)
        m_buf[(size_t)(tok0 + t) * NOUT + j] = acc[t][j] * inv + bias[j];
    }
  }
}

// ---------------------------------------------------------------------------
// Kernel C: heads + Sinkhorn. 16 lanes per token (one per 4x4 element).
//   row sums: shfl_xor 1,2 (c bits); col sums: shfl_xor 4,8 (r bits).
// ---------------------------------------------------------------------------
__global__ __launch_bounds__(256) void k_heads(
    const float* __restrict__ m_buf, const float* __restrict__ a_pre_p,
    const float* __restrict__ a_post_p, const float* __restrict__ a_res_p,
    float* __restrict__ out) {
  int gid = blockIdx.x * 256 + threadIdx.x;
  int tok = gid >> 4;
  int e   = gid & 15;          // r*4 + c

  float a_res = *a_res_p;
  float M = expf(a_res * m_buf[tok * NOUT + 2 * NEXP + e]);
#pragma unroll 1
  for (int it = 0; it < SK_ITERS; it++) {
    float rs = M + __shfl_xor(M, 1, 64);
    rs += __shfl_xor(rs, 2, 64);
    M = M / (rs + 1e-12f);
    float cs = M + __shfl_xor(M, 4, 64);
    cs += __shfl_xor(cs, 8, 64);
    M = M / (cs + 1e-12f);
  }
  out[2 * NTOK * NEXP + tok * 16 + e] = M;   // h_res at offset 131072

  if (e < NEXP) {
    float z = (*a_pre_p) * m_buf[tok * NOUT + e];
    out[tok * NEXP + e] = 1.0f / (1.0f + expf(-z));
  } else if (e < 2 * NEXP) {
    int j = e - NEXP;
    float z = (*a_post_p) * m_buf[tok * NOUT + NEXP + j];
    out[NTOK * NEXP + tok * NEXP + j] = 2.0f / (1.0f + expf(-z));
  }
}

// ---------------------------------------------------------------------------
extern "C" void kernel_launch(void* const* d_in, const int* in_sizes, int n_in,
                              void* d_out, int out_size, void* d_ws, size_t ws_size,
                              hipStream_t stream) {
  const float* x      = (const float*)d_in[0];
  const float* scale  = (const float*)d_in[1];
  const float* phi    = (const float*)d_in[2];
  const float* bias   = (const float*)d_in[3];
  const float* a_pre  = (const float*)d_in[4];
  const float* a_post = (const float*)d_in[5];
  const float* a_res  = (const float*)d_in[6];
  float* out = (float*)d_out;

  float* phiT  = (float*)d_ws;            // 24*4096 = 98304 floats
  float* m_buf = phiT + NOUT * STREAM;    // 16384*24 = 393216 floats

  k_transpose_scale<<<(NOUT * STREAM) / 256, 256, 0, stream>>>(phi, scale, phiT);
  // 16384 tokens / (4 waves * 4 tokens) = 1024 blocks
  k_matvec<<<NTOK / (4 * T_W), 256, 0, stream>>>(x, phiT, bias, m_buf);
  k_heads<<<(NTOK * 16) / 256, 256, 0, stream>>>(m_buf, a_pre, a_post, a_res, out);
}

// Round 5
// 490.368 us; speedup vs baseline: 1.0125x; 1.0125x over previous
//
#include <hip/hip_runtime.h>
#include <math.h>

// Problem constants (fixed by the reference):
#define NEXP 4               // n
#define STREAM 4096          // N*C
#define NOUT 24              // n*n + 2n
#define NTOK 16384           // B*L
#define SK_ITERS 20

// Kernel B: barrier-free, LDS-free. Block = 256 thr (4 waves), 8 tokens/block.
//   Wave w computes output columns j in [6w, 6w+6) for all 8 tokens; lanes
//   split K (lane l owns float4 #l of each 256-float step). Every wave loads
//   all 8 tokens' x (3 of 4 waves hit L1 on the same lines -> HBM reads x
//   once). Register budget: acc 48 + pv 24 + xv 32 ~= 110 < 128-VGPR cliff,
//   so the compiler keeps all 14 loads/step in flight (R4 post-mortem: at
//   acc=96 it clamped to 104 VGPRs and serialized loads -> 228 us).
#define T_B 8                // tokens per block
#define NSTEP (STREAM / 256) // 16 K-steps of 256 floats (64 lanes x float4)

// ---------------------------------------------------------------------------
// Kernel A: phiT[j][k] = scale[k] * phi[k][j]   (24 x 4096, transposed+scaled)
// ---------------------------------------------------------------------------
__global__ __launch_bounds__(256) void k_transpose_scale(
    const float* __restrict__ phi, const float* __restrict__ scale,
    float* __restrict__ phiT) {
  int flat = blockIdx.x * 256 + threadIdx.x;   // 0..98303, flat = k*24 + j
  int k = flat / NOUT;
  int j = flat - k * NOUT;
  phiT[j * STREAM + k] = phi[flat] * scale[k];
}

// ---------------------------------------------------------------------------
// Kernel B: per token, sumsq + 24-way dot, m = dot/rms + bias -> m_buf
// ---------------------------------------------------------------------------
__global__ __launch_bounds__(256) void k_matvec(
    const float* __restrict__ x, const float* __restrict__ phiT,
    const float* __restrict__ bias, float* __restrict__ m_buf) {
  const int w    = threadIdx.x >> 6;      // wave id 0..3 -> j0 = 6w
  const int lane = threadIdx.x & 63;
  const int tok0 = blockIdx.x * T_B;
  const int j0   = 6 * w;

  const float4* x4    = (const float4*)x;
  const float4* phiT4 = (const float4*)phiT;

  float acc[T_B][6];
  float ssq[T_B];
#pragma unroll
  for (int t = 0; t < T_B; t++) {
    ssq[t] = 0.0f;
#pragma unroll
    for (int jj = 0; jj < 6; jj++) acc[t][jj] = 0.0f;
  }

  for (int i = 0; i < NSTEP; i++) {
    const int kofs = i * 64 + lane;       // float4 index within a 4096-row
    float4 xv[T_B];
#pragma unroll
    for (int t = 0; t < T_B; t++)
      xv[t] = x4[(size_t)(tok0 + t) * (STREAM / 4) + kofs];
    float4 pv[6];
#pragma unroll
    for (int jj = 0; jj < 6; jj++)
      pv[jj] = phiT4[(j0 + jj) * (STREAM / 4) + kofs];

#pragma unroll
    for (int t = 0; t < T_B; t++)
      ssq[t] += xv[t].x * xv[t].x + xv[t].y * xv[t].y +
                xv[t].z * xv[t].z + xv[t].w * xv[t].w;
#pragma unroll
    for (int t = 0; t < T_B; t++) {
#pragma unroll
      for (int jj = 0; jj < 6; jj++) {
        float a = acc[t][jj];
        a = fmaf(xv[t].x, pv[jj].x, a);
        a = fmaf(xv[t].y, pv[jj].y, a);
        a = fmaf(xv[t].z, pv[jj].z, a);
        a = fmaf(xv[t].w, pv[jj].w, a);
        acc[t][jj] = a;
      }
    }
  }

  // ---- butterfly reduce across the 64 lanes (all lanes end with totals) ----
#pragma unroll
  for (int d = 1; d < 64; d <<= 1) {
#pragma unroll
    for (int t = 0; t < T_B; t++) {
      ssq[t] += __shfl_xor(ssq[t], d, 64);
#pragma unroll
      for (int jj = 0; jj < 6; jj++)
        acc[t][jj] += __shfl_xor(acc[t][jj], d, 64);
    }
  }

  // ---- write m: lane t*6+jj stores token tok0+t, column j0+jj ----
#pragma unroll
  for (int t = 0; t < T_B; t++) {
    float inv = 1.0f / sqrtf(ssq[t] * (1.0f / STREAM) + 1e-20f);
#pragma unroll
    for (int jj = 0; jj < 6; jj++) {
      if (lane == t * 6 + jj) {
        int j = j0 + jj;
        m_buf[(size_t)(tok0 + t) * NOUT + j] = acc[t][jj] * inv + bias[j];
      }
    }
  }
}

// ---------------------------------------------------------------------------
// Kernel C: heads + Sinkhorn. 16 lanes per token (one per 4x4 element).
//   row sums: shfl_xor 1,2 (c bits); col sums: shfl_xor 4,8 (r bits).
// ---------------------------------------------------------------------------
__global__ __launch_bounds__(256) void k_heads(
    const float* __restrict__ m_buf, const float* __restrict__ a_pre_p,
    const float* __restrict__ a_post_p, const float* __restrict__ a_res_p,
    float* __restrict__ out) {
  int gid = blockIdx.x * 256 + threadIdx.x;
  int tok = gid >> 4;
  int e   = gid & 15;          // r*4 + c

  float a_res = *a_res_p;
  float M = expf(a_res * m_buf[tok * NOUT + 2 * NEXP + e]);
#pragma unroll 1
  for (int it = 0; it < SK_ITERS; it++) {
    float rs = M + __shfl_xor(M, 1, 64);
    rs += __shfl_xor(rs, 2, 64);
    M = M / (rs + 1e-12f);
    float cs = M + __shfl_xor(M, 4, 64);
    cs += __shfl_xor(cs, 8, 64);
    M = M / (cs + 1e-12f);
  }
  out[2 * NTOK * NEXP + tok * 16 + e] = M;   // h_res at offset 131072

  if (e < NEXP) {
    float z = (*a_pre_p) * m_buf[tok * NOUT + e];
    out[tok * NEXP + e] = 1.0f / (1.0f + expf(-z));
  } else if (e < 2 * NEXP) {
    int j = e - NEXP;
    float z = (*a_post_p) * m_buf[tok * NOUT + NEXP + j];
    out[NTOK * NEXP + tok * NEXP + j] = 2.0f / (1.0f + expf(-z));
  }
}

// ---------------------------------------------------------------------------
extern "C" void kernel_launch(void* const* d_in, const int* in_sizes, int n_in,
                              void* d_out, int out_size, void* d_ws, size_t ws_size,
                              hipStream_t stream) {
  const float* x      = (const float*)d_in[0];
  const float* scale  = (const float*)d_in[1];
  const float* phi    = (const float*)d_in[2];
  const float* bias   = (const float*)d_in[3];
  const float* a_pre  = (const float*)d_in[4];
  const float* a_post = (const float*)d_in[5];
  const float* a_res  = (const float*)d_in[6];
  float* out = (float*)d_out;

  float* phiT  = (float*)d_ws;            // 24*4096 = 98304 floats
  float* m_buf = phiT + NOUT * STREAM;    // 16384*24 = 393216 floats

  k_transpose_scale<<<(NOUT * STREAM) / 256, 256, 0, stream>>>(phi, scale, phiT);
  k_matvec<<<NTOK / T_B, 256, 0, stream>>>(x, phiT, bias, m_buf);   // 2048 blocks
  k_heads<<<(NTOK * 16) / 256, 256, 0, stream>>>(m_buf, a_pre, a_post, a_res, out);
}

// Round 6
// 455.080 us; speedup vs baseline: 1.0910x; 1.0775x over previous
//
#include <hip/hip_runtime.h>
#include <math.h>

// Problem constants (fixed by the reference):
#define NEXP 4               // n
#define STREAM 4096          // N*C
#define NOUT 24              // n*n + 2n
#define NTOK 16384           // B*L
#define SK_ITERS 20

#define T_B 8                // tokens per block
#define NSTEP (STREAM / 256) // 16 K-steps of 256 floats (64 lanes x float4)

// ---------------------------------------------------------------------------
// Kernel A: phiT[j][k] = scale[k] * phi[k][j]   (24 x 4096, transposed+scaled)
// ---------------------------------------------------------------------------
__global__ __launch_bounds__(256) void k_transpose_scale(
    const float* __restrict__ phi, const float* __restrict__ scale,
    float* __restrict__ phiT) {
  int flat = blockIdx.x * 256 + threadIdx.x;   // 0..98303, flat = k*24 + j
  int k = flat / NOUT;
  int j = flat - k * NOUT;
  phiT[j * STREAM + k] = phi[flat] * scale[k];
}

// ---------------------------------------------------------------------------
// Kernel B: per token, sumsq + 24-way dot, m = dot/rms + bias -> m_buf
//   Barrier-free, LDS-free; wave w does j in [6w,6w+6) for all 8 tokens.
//   EXPLICIT register double-buffer: step i+1's 14 loads (8 xv + 6 pv) are
//   issued before step i's FMA phase consumes buffer A, so 14 KB/wave stays
//   in flight regardless of the scheduler's pressure heuristic (R4/R5
//   post-mortem: default regalloc sank loads next to consumers -> fully
//   serialized latency, 228-231 us). __launch_bounds__(256,1) lifts the
//   VGPR cap to 512 so the ~190-reg working set fits without spill.
// ---------------------------------------------------------------------------
__global__ __launch_bounds__(256, 1) void k_matvec(
    const float* __restrict__ x, const float* __restrict__ phiT,
    const float* __restrict__ bias, float* __restrict__ m_buf) {
  const int w    = threadIdx.x >> 6;      // wave id 0..3 -> j0 = 6w
  const int lane = threadIdx.x & 63;
  const int tok0 = blockIdx.x * T_B;
  const int j0   = 6 * w;

  const float4* x4    = (const float4*)x;
  const float4* phiT4 = (const float4*)phiT;

  float acc[T_B][6];
  float ssq[T_B];
#pragma unroll
  for (int t = 0; t < T_B; t++) {
    ssq[t] = 0.0f;
#pragma unroll
    for (int jj = 0; jj < 6; jj++) acc[t][jj] = 0.0f;
  }

  float4 xvA[T_B], pvA[6], xvB[T_B], pvB[6];

  auto loadstep = [&](int i, float4 (&xv)[T_B], float4 (&pv)[6]) {
    const int kofs = i * 64 + lane;       // float4 index within a 4096-row
#pragma unroll
    for (int t = 0; t < T_B; t++)
      xv[t] = x4[(size_t)(tok0 + t) * (STREAM / 4) + kofs];
#pragma unroll
    for (int jj = 0; jj < 6; jj++)
      pv[jj] = phiT4[(j0 + jj) * (STREAM / 4) + kofs];
  };

  auto fmastep = [&](const float4 (&xv)[T_B], const float4 (&pv)[6]) {
#pragma unroll
    for (int t = 0; t < T_B; t++)
      ssq[t] += xv[t].x * xv[t].x + xv[t].y * xv[t].y +
                xv[t].z * xv[t].z + xv[t].w * xv[t].w;
#pragma unroll
    for (int t = 0; t < T_B; t++) {
#pragma unroll
      for (int jj = 0; jj < 6; jj++) {
        float a = acc[t][jj];
        a = fmaf(xv[t].x, pv[jj].x, a);
        a = fmaf(xv[t].y, pv[jj].y, a);
        a = fmaf(xv[t].z, pv[jj].z, a);
        a = fmaf(xv[t].w, pv[jj].w, a);
        acc[t][jj] = a;
      }
    }
  };

  loadstep(0, xvA, pvA);
#pragma unroll 1
  for (int i = 0; i < NSTEP; i += 2) {
    loadstep(i + 1, xvB, pvB);            // prefetch odd step (i+1 <= 15)
    fmastep(xvA, pvA);
    if (i + 2 < NSTEP) loadstep(i + 2, xvA, pvA);   // prefetch next even
    fmastep(xvB, pvB);
  }

  // ---- butterfly reduce across the 64 lanes (all lanes end with totals) ----
#pragma unroll
  for (int d = 1; d < 64; d <<= 1) {
#pragma unroll
    for (int t = 0; t < T_B; t++) {
      ssq[t] += __shfl_xor(ssq[t], d, 64);
#pragma unroll
      for (int jj = 0; jj < 6; jj++)
        acc[t][jj] += __shfl_xor(acc[t][jj], d, 64);
    }
  }

  // ---- write m: lane t*6+jj stores token tok0+t, column j0+jj ----
#pragma unroll
  for (int t = 0; t < T_B; t++) {
    float inv = 1.0f / sqrtf(ssq[t] * (1.0f / STREAM) + 1e-20f);
#pragma unroll
    for (int jj = 0; jj < 6; jj++) {
      if (lane == t * 6 + jj) {
        int j = j0 + jj;
        m_buf[(size_t)(tok0 + t) * NOUT + j] = acc[t][jj] * inv + bias[j];
      }
    }
  }
}

// ---------------------------------------------------------------------------
// Kernel C: heads + Sinkhorn. 16 lanes per token (one per 4x4 element).
//   row sums: shfl_xor 1,2 (c bits); col sums: shfl_xor 4,8 (r bits).
// ---------------------------------------------------------------------------
__global__ __launch_bounds__(256) void k_heads(
    const float* __restrict__ m_buf, const float* __restrict__ a_pre_p,
    const float* __restrict__ a_post_p, const float* __restrict__ a_res_p,
    float* __restrict__ out) {
  int gid = blockIdx.x * 256 + threadIdx.x;
  int tok = gid >> 4;
  int e   = gid & 15;          // r*4 + c

  float a_res = *a_res_p;
  float M = expf(a_res * m_buf[tok * NOUT + 2 * NEXP + e]);
#pragma unroll 1
  for (int it = 0; it < SK_ITERS; it++) {
    float rs = M + __shfl_xor(M, 1, 64);
    rs += __shfl_xor(rs, 2, 64);
    M = M / (rs + 1e-12f);
    float cs = M + __shfl_xor(M, 4, 64);
    cs += __shfl_xor(cs, 8, 64);
    M = M / (cs + 1e-12f);
  }
  out[2 * NTOK * NEXP + tok * 16 + e] = M;   // h_res at offset 131072

  if (e < NEXP) {
    float z = (*a_pre_p) * m_buf[tok * NOUT + e];
    out[tok * NEXP + e] = 1.0f / (1.0f + expf(-z));
  } else if (e < 2 * NEXP) {
    int j = e - NEXP;
    float z = (*a_post_p) * m_buf[tok * NOUT + NEXP + j];
    out[NTOK * NEXP + tok * NEXP + j] = 2.0f / (1.0f + expf(-z));
  }
}

// ---------------------------------------------------------------------------
extern "C" void kernel_launch(void* const* d_in, const int* in_sizes, int n_in,
                              void* d_out, int out_size, void* d_ws, size_t ws_size,
                              hipStream_t stream) {
  const float* x      = (const float*)d_in[0];
  const float* scale  = (const float*)d_in[1];
  const float* phi    = (const float*)d_in[2];
  const float* bias   = (const float*)d_in[3];
  const float* a_pre  = (const float*)d_in[4];
  const float* a_post = (const float*)d_in[5];
  const float* a_res  = (const float*)d_in[6];
  float* out = (float*)d_out;

  float* phiT  = (float*)d_ws;            // 24*4096 = 98304 floats
  float* m_buf = phiT + NOUT * STREAM;    // 16384*24 = 393216 floats

  k_transpose_scale<<<(NOUT * STREAM) / 256, 256, 0, stream>>>(phi, scale, phiT);
  k_matvec<<<NTOK / T_B, 256, 0, stream>>>(x, phiT, bias, m_buf);   // 2048 blocks
  k_heads<<<(NTOK * 16) / 256, 256, 0, stream>>>(m_buf, a_pre, a_post, a_res, out);
}